// Round 9
// baseline (543.082 us; speedup 1.0000x reference)
//
#include <hip/hip_runtime.h>
#include <hip/hip_bf16.h>

#define B_      2
#define S_      1024
#define HID     4096
#define NH      32
#define NKV     8
#define D_      128
#define G_      4
#define WINDOW  512
#define QKV_OUT 6144      // (NH + 2*NKV) * D
#define M_TOT   2048      // B * S
#define CH      32        // kv chunk length in attention
#define VSTR    40        // transposed-V row stride (80 B: 16B-aligned frags, 2-way banks)

typedef __bf16 bf16x8 __attribute__((ext_vector_type(8)));
typedef float  f32x4  __attribute__((ext_vector_type(4)));
typedef unsigned short u16x8 __attribute__((ext_vector_type(8)));

#define AS1 __attribute__((address_space(1)))
#define AS3 __attribute__((address_space(3)))

static __device__ __forceinline__ float bf2f(unsigned short u) {
    union { unsigned int i; float f; } v; v.i = ((unsigned int)u) << 16; return v.f;
}
static __device__ __forceinline__ unsigned short f2bf(float f) {
    union { float f; unsigned int i; } v; v.f = f;
    unsigned int x = v.i;
    return (unsigned short)((x + 0x7fffu + ((x >> 16) & 1u)) >> 16);
}
static __device__ __forceinline__ void gl2lds16(const void* g, void* l) {
    __builtin_amdgcn_global_load_lds((const AS1 void*)g, (AS3 void*)l, 16, 0, 0);
}

// ---------------- fp32 -> bf16 bulk conversion (RTNE) ----------------
__global__ __launch_bounds__(256)
void conv_f32_bf16(const float* __restrict__ src, unsigned short* __restrict__ dst, int n8)
{
    int i = blockIdx.x * 256 + threadIdx.x;
    if (i >= n8) return;
    const float* p = src + (size_t)i * 8;
    float4 f0 = *(const float4*)p;
    float4 f1 = *(const float4*)(p + 4);
    u16x8 h;
    h[0]=f2bf(f0.x); h[1]=f2bf(f0.y); h[2]=f2bf(f0.z); h[3]=f2bf(f0.w);
    h[4]=f2bf(f1.x); h[5]=f2bf(f1.y); h[6]=f2bf(f1.z); h[7]=f2bf(f1.w);
    *(u16x8*)&dst[(size_t)i * 8] = h;
}

// ---------------- fused 3-tensor fp32 -> bf16 conversion (one launch) ----------------
// n8h/n8q/n8o are all multiples of 256 -> branch is block-uniform.
__global__ __launch_bounds__(256)
void conv3_f32_bf16(const float* __restrict__ s0, unsigned short* __restrict__ d0, int n0,
                    const float* __restrict__ s1, unsigned short* __restrict__ d1, int n1,
                    const float* __restrict__ s2, unsigned short* __restrict__ d2, int n2)
{
    int i = blockIdx.x * 256 + threadIdx.x;
    const float* s; unsigned short* d;
    if (i < n0)                { s = s0; d = d0; }
    else if ((i -= n0) < n1)   { s = s1; d = d1; }
    else if ((i -= n1) < n2)   { s = s2; d = d2; }
    else return;
    const float* p = s + (size_t)i * 8;
    float4 f0 = *(const float4*)p;
    float4 f1 = *(const float4*)(p + 4);
    u16x8 h;
    h[0]=f2bf(f0.x); h[1]=f2bf(f0.y); h[2]=f2bf(f0.z); h[3]=f2bf(f0.w);
    h[4]=f2bf(f1.x); h[5]=f2bf(f1.y); h[6]=f2bf(f1.z); h[7]=f2bf(f1.w);
    *(u16x8*)&d[(size_t)i * 8] = h;
}

// ================= 256 x (NT*64) 4-phase pipelined GEMM =================
// r8-proven (passing, QKV 105us @ MfmaUtil 41 / 0 conflicts; O-proj < 105us).
// UNCHANGED this round -- serves as the control.  Full design notes in r8.
#define MFMA_CL(MT0, MT1, AR)                                                          \
    __builtin_amdgcn_s_setprio(1);                                                     \
    _Pragma("unroll")                                                                  \
    for (int ks = 0; ks < 2; ++ks) {                                                   \
        _Pragma("unroll")                                                              \
        for (int nt = 0; nt < NT; ++nt) {                                              \
            acc[MT0][nt] = __builtin_amdgcn_mfma_f32_16x16x32_bf16(AR[0][ks], bC[nt][ks], acc[MT0][nt], 0, 0, 0); \
            acc[MT1][nt] = __builtin_amdgcn_mfma_f32_16x16x32_bf16(AR[1][ks], bC[nt][ks], acc[MT1][nt], 0, 0, 0); \
        }                                                                              \
    }                                                                                  \
    __builtin_amdgcn_s_setprio(0);

#define SCHED __builtin_amdgcn_sched_barrier(0)
#define WAITLGKM(N) do { asm volatile("s_waitcnt lgkmcnt(" #N ")" ::: "memory"); SCHED; } while (0)
#define WAITVM_STEADY do {                                                             \
    if constexpr (NT == 3) { asm volatile("s_waitcnt vmcnt(5)" ::: "memory"); }        \
    else                   { asm volatile("s_waitcnt vmcnt(4)" ::: "memory"); }        \
} while (0)
#define BARRIER do { SCHED; __builtin_amdgcn_s_barrier(); SCHED; } while (0)

template<int NT, bool C_BF16>
__global__ __launch_bounds__(512, 2)
void gemm256_8ph(const unsigned short* __restrict__ A,
                 const unsigned short* __restrict__ Bw,
                 const float* __restrict__ bias,
                 void* __restrict__ Cv,
                 int M, int N, int K)
{
    __shared__ __attribute__((aligned(1024))) unsigned short lds[32768 + NT * 8192];

    const int tid  = threadIdx.x;
    const int lane = tid & 63;
    const int w    = tid >> 6;        // 0..7
    const int m_   = w >> 2;          // 0..1  (M half, 128 rows)
    const int n_   = w & 3;           // 0..3  (N quarter, NT*16 cols)
    const int lm   = lane & 15, quad = lane >> 4;
    const int m0   = blockIdx.y * 256, n0 = blockIdx.x * (NT * 64);
    const int nkt  = K >> 6;          // BK=64 tiles (requires nkt >= 3)

    const int srow = lane >> 3;                  // 0..7 row within 8-row instr
    const int scol = ((lane & 7) ^ srow) * 8;    // elem col within BK=64 (inverse swizzle)

    const int arow0 = m0 + m_ * 128 + n_ * 16;   // staged A rows n_*16..+15
    const int arow1 = arow0 + 64;                // staged A rows 64+n_*16..+15
    const int brow  = n0 + w * (NT * 8);         // staged B rows, NT*8 per wave

    const int ldsAr = m_ * 8192;                            // A read base (own half)
    const int ldsA0 = ldsAr + n_ * 1024;                    // A stage rp0
    const int ldsA1 = ldsA0 + 4096;                         // A stage rp1
    const int ldsBs = 32768 + w * (NT * 512);               // B stage base
    const int ldsBr = 32768 + n_ * (NT * 1024);             // B read base

    f32x4 acc[8][NT] = {};
    bf16x8 bC[NT][2];          // B frags, whole tile (read at tile boundary)
    bf16x8 aP[2][2], aQ[2][2]; // A frag ping-pong (one phase ahead)

    auto stA = [&](int T, int rp) {
        const int k0   = T << 6;
        const int bufo = (T & 1) << 14;
        const int rb   = (rp ? arow1 : arow0) + srow;
        const int lb   = (rp ? ldsA1 : ldsA0) + bufo + lane * 8;
        gl2lds16(&A[(size_t)rb * K + k0 + scol],       &lds[lb]);
        gl2lds16(&A[(size_t)(rb + 8) * K + k0 + scol], &lds[lb + 512]);
    };
    auto stB = [&](int T, int pr) {   // pr0: first NT-1 loads, pr1: last 8 rows (1 load)
        const int k0   = T << 6;
        const int bufo = (T & 1) * (NT * 4096);
        if (pr == 0) {
            #pragma unroll
            for (int j = 0; j < NT - 1; ++j) {
                const int rb = brow + j * 8 + srow;
                gl2lds16(&Bw[(size_t)rb * K + k0 + scol],
                         &lds[ldsBs + j * 512 + bufo + lane * 8]);
            }
        } else {
            const int rb = brow + (NT - 1) * 8 + srow;
            gl2lds16(&Bw[(size_t)rb * K + k0 + scol],
                     &lds[ldsBs + (NT - 1) * 512 + bufo + lane * 8]);
        }
    };
    auto rdA = [&](int T, int mt, int ks) -> bf16x8 {
        int e = (mt * 16 + lm) * 64 + ks * 32 + quad * 8;
        e ^= ((e >> 6) & 7) << 3;                 // slot ^= row&7 (conflict-free)
        return *(const bf16x8*)&lds[((T & 1) << 14) + ldsAr + e];
    };
    auto rdB = [&](int T, int nt, int ks) -> bf16x8 {
        int e = (nt * 16 + lm) * 64 + ks * 32 + quad * 8;
        e ^= ((e >> 6) & 7) << 3;                 // all bases 512-elem mult: bits 6-8 clean
        return *(const bf16x8*)&lds[(T & 1) * (NT * 4096) + ldsBr + e];
    };
    auto rdBoundary = [&](int T) {
        #pragma unroll
        for (int nt = 0; nt < NT; ++nt)
            #pragma unroll
            for (int ks = 0; ks < 2; ++ks) bC[nt][ks] = rdB(T, nt, ks);
        #pragma unroll
        for (int ks = 0; ks < 2; ++ks) { aP[0][ks] = rdA(T, 0, ks); aP[1][ks] = rdA(T, 1, ks); }
    };

    // prologue: tile0 full (NT+4 loads) + tile1 first NT+2; drain tile0
    stB(0, 0); stB(0, 1); stA(0, 0); stA(0, 1);
    stB(1, 0); stB(1, 1); stA(1, 0);
    WAITVM_STEADY;
    BARRIER;
    rdBoundary(0);
    SCHED;

    #pragma unroll 1
    for (int i = 0; i < nkt; ++i) {
        // ---- P1: MFMA mt0,1 (aP); prefetch mt2,3 -> aQ ----
        if (i + 1 < nkt) stA(i + 1, 1);
        #pragma unroll
        for (int ks = 0; ks < 2; ++ks) { aQ[0][ks] = rdA(i, 2, ks); aQ[1][ks] = rdA(i, 3, ks); }
        SCHED;
        WAITLGKM(4);          // drains boundary (2NT+4); leaves aQ's 4
        MFMA_CL(0, 1, aP)
        BARRIER;
        // ---- P2: MFMA mt2,3 (aQ); prefetch mt4,5 -> aP ----  (no end barrier)
        if (i + 2 < nkt) stB(i + 2, 0);
        #pragma unroll
        for (int ks = 0; ks < 2; ++ks) { aP[0][ks] = rdA(i, 4, ks); aP[1][ks] = rdA(i, 5, ks); }
        SCHED;
        WAITLGKM(4);          // drains aQ's 4; leaves aP's 4
        MFMA_CL(2, 3, aQ)
        // ---- P3: MFMA mt4,5 (aP); prefetch mt6,7 -> aQ ----  (no end barrier)
        if (i + 2 < nkt) stB(i + 2, 1);
        #pragma unroll
        for (int ks = 0; ks < 2; ++ks) { aQ[0][ks] = rdA(i, 6, ks); aQ[1][ks] = rdA(i, 7, ks); }
        SCHED;
        WAITLGKM(4);
        MFMA_CL(4, 5, aP)
        // ---- P4: MFMA mt6,7 (aQ); boundary vmcnt; boundary reads for i+1 ----
        if (i + 2 < nkt) stA(i + 2, 0);
        SCHED;
        WAITLGKM(0);          // drains aQ's 4 (only lgkm outstanding)
        MFMA_CL(6, 7, aQ)
        SCHED;
        if (i + 2 < nkt)      { WAITVM_STEADY; }
        else if (i + 1 < nkt) { asm volatile("s_waitcnt vmcnt(0)" ::: "memory"); }
        BARRIER;
        if (i + 1 < nkt) rdBoundary(i + 1);
        SCHED;
    }

    #pragma unroll
    for (int nt = 0; nt < NT; ++nt) {
        const int col = n0 + n_ * (NT * 16) + nt * 16 + lm;
        const float bv = bias[col];
        #pragma unroll
        for (int mt = 0; mt < 8; ++mt) {
            const int rowb = m0 + m_ * 128 + mt * 16 + quad * 4;
            #pragma unroll
            for (int r = 0; r < 4; ++r) {
                const float val = acc[mt][nt][r] + bv;
                if (C_BF16)
                    ((unsigned short*)Cv)[(size_t)(rowb + r) * N + col] = f2bf(val);
                else
                    ((float*)Cv)[(size_t)(rowb + r) * N + col] = val;
            }
        }
    }
}

// ---------------- fallback GEMM (fp32 staging, round-3 proven) ----------------
template<bool A_BF16, bool C_BF16>
__global__ __launch_bounds__(256)
void gemm_bt_bias(const void* __restrict__ Av,
                  const float* __restrict__ Bw,
                  const float* __restrict__ bias,
                  void* __restrict__ Cv,
                  int M, int N, int K)
{
    __shared__ unsigned short As[128 * 40];
    __shared__ unsigned short Bs[128 * 40];

    const int tid  = threadIdx.x;
    const int m0   = blockIdx.y * 128;
    const int n0   = blockIdx.x * 128;
    const int wave = tid >> 6, lane = tid & 63;
    const int wm   = (wave >> 1) * 64;
    const int wn   = (wave & 1) * 64;
    const int lm   = lane & 15, quad = lane >> 4;

    f32x4 acc[4][4] = {};

    for (int k0 = 0; k0 < K; k0 += 32) {
        __syncthreads();
        #pragma unroll
        for (int c = 0; c < 2; ++c) {
            int chunk = tid + c * 256;
            int row   = chunk >> 2;
            int off   = (chunk & 3) * 8;
            if (A_BF16) {
                *(u16x8*)&As[row * 40 + off] =
                    *(const u16x8*)&((const unsigned short*)Av)[(size_t)(m0 + row) * K + k0 + off];
            } else {
                const float* ap = &((const float*)Av)[(size_t)(m0 + row) * K + k0 + off];
                float4 f0 = *(const float4*)ap;
                float4 f1 = *(const float4*)(ap + 4);
                u16x8 h;
                h[0]=f2bf(f0.x); h[1]=f2bf(f0.y); h[2]=f2bf(f0.z); h[3]=f2bf(f0.w);
                h[4]=f2bf(f1.x); h[5]=f2bf(f1.y); h[6]=f2bf(f1.z); h[7]=f2bf(f1.w);
                *(u16x8*)&As[row * 40 + off] = h;
            }
            {
                const float* bp = &Bw[(size_t)(n0 + row) * K + k0 + off];
                float4 f0 = *(const float4*)bp;
                float4 f1 = *(const float4*)(bp + 4);
                u16x8 h;
                h[0]=f2bf(f0.x); h[1]=f2bf(f0.y); h[2]=f2bf(f0.z); h[3]=f2bf(f0.w);
                h[4]=f2bf(f1.x); h[5]=f2bf(f1.y); h[6]=f2bf(f1.z); h[7]=f2bf(f1.w);
                *(u16x8*)&Bs[row * 40 + off] = h;
            }
        }
        __syncthreads();

        bf16x8 afr[4], bfr[4];
        #pragma unroll
        for (int i = 0; i < 4; ++i)
            afr[i] = *(const bf16x8*)&As[(wm + i * 16 + lm) * 40 + quad * 8];
        #pragma unroll
        for (int j = 0; j < 4; ++j)
            bfr[j] = *(const bf16x8*)&Bs[(wn + j * 16 + lm) * 40 + quad * 8];

        #pragma unroll
        for (int i = 0; i < 4; ++i)
            #pragma unroll
            for (int j = 0; j < 4; ++j)
                acc[i][j] = __builtin_amdgcn_mfma_f32_16x16x32_bf16(afr[i], bfr[j], acc[i][j], 0, 0, 0);
    }

    #pragma unroll
    for (int j = 0; j < 4; ++j) {
        int col = n0 + wn + j * 16 + lm;
        float bv = bias[col];
        #pragma unroll
        for (int i = 0; i < 4; ++i) {
            int rowb = m0 + wm + i * 16 + quad * 4;
            #pragma unroll
            for (int r = 0; r < 4; ++r) {
                float val = acc[i][j][r] + bv;
                if (C_BF16)
                    ((unsigned short*)Cv)[(size_t)(rowb + r) * N + col] = f2bf(val);
                else
                    ((float*)Cv)[(size_t)(rowb + r) * N + col] = val;
            }
        }
    }
}

// ---------------- Flash-style MFMA attention with FUSED RoPE ----------------
// r8 -> r9: rope_kernel deleted; rotation fused here.  qkv_ws holds UN-roped
// q/k; rope'd values exist only in-register (Q) / in-LDS (K).  Numerics are
// bit-identical to the old separate kernel: same bf2f -> fp32 rotate -> f2bf
// chain, same cos/sin table reads.
//   Q: lane owns row rw0+lm, dims kb*32+quad*8+e.  The d <-> d+64 rope pair
//      is qf[kb] <-> qf[kb+2] IN THE SAME LANE (d+64 = (kb+2)*32 + same rest)
//      -> pure in-register rotation, once per block.
//   K: staged per chunk; partner element at d0^64 is a second u16x8 load of
//      the same row (L2-hot), rotation applied before the LDS write.  The
//      d0<64 branch is thread-uniform (d0 = (idx&15)*8).
//   V: untouched by rope (reference applies rope to q,k only).
__global__ __launch_bounds__(256)
void attn_mfma(const unsigned short* __restrict__ qkv,
               const float* __restrict__ cosb,
               const float* __restrict__ sinb,
               unsigned short* __restrict__ attn)
{
    __shared__ unsigned short Kl[CH * 136];
    __shared__ unsigned short Vt[128 * VSTR];    // [dim][row] transposed
    __shared__ unsigned short Pl[4][16 * 40];

    const int tid  = threadIdx.x;
    const int wave = tid >> 6, lane = tid & 63;
    const int lm   = lane & 15, quad = lane >> 4;
    const int h    = blockIdx.y;
    const int b    = blockIdx.z;
    const int kvh  = h >> 2;
    const int r0b  = blockIdx.x * 64;
    const int rw0  = r0b + wave * 16;

    const size_t qkv_b = (size_t)b * S_ * QKV_OUT;
    const float SCL = 0.12751974f;   // (1/sqrt(128)) * log2(e)

    // Q load + in-register rope
    bf16x8 qf[4];
    {
        const unsigned short* qrow = qkv + qkv_b + (size_t)(rw0 + lm) * QKV_OUT + h * D_ + quad * 8;
        u16x8 qr[4];
        #pragma unroll
        for (int kb = 0; kb < 4; ++kb)
            qr[kb] = *(const u16x8*)(qrow + kb * 32);
        const float* cb = cosb + (size_t)(rw0 + lm) * D_ + quad * 8;
        const float* sb = sinb + (size_t)(rw0 + lm) * D_ + quad * 8;
        u16x8 qo[4];
        #pragma unroll
        for (int kb = 0; kb < 2; ++kb)
            #pragma unroll
            for (int e = 0; e < 8; ++e) {
                int d = kb * 32 + e;
                float x1 = bf2f(qr[kb][e]);
                float x2 = bf2f(qr[kb + 2][e]);
                qo[kb][e]     = f2bf(x1 * cb[d]      - x2 * sb[d]);
                qo[kb + 2][e] = f2bf(x2 * cb[d + 64] + x1 * sb[d + 64]);
            }
        #pragma unroll
        for (int kb = 0; kb < 4; ++kb)
            qf[kb] = *(const bf16x8*)&qo[kb];
    }

    f32x4 O[8] = {};
    float mrow[4] = {-1e30f, -1e30f, -1e30f, -1e30f};
    float lrow[4] = {0.f, 0.f, 0.f, 0.f};

    const int c0   = max(0, r0b - (WINDOW - 1)) & ~(CH - 1);
    const int cend = r0b + 64 - CH;

    for (int c = c0; c <= cend; c += CH) {
        __syncthreads();
        // K: rows c..c+31 with fused rope (partner at d0^64), padded-136 LDS
        #pragma unroll
        for (int p = 0; p < 2; ++p) {
            int idx = tid + p * 256;
            int row = idx >> 4;
            int d0  = (idx & 15) * 8;
            const unsigned short* kr = qkv + qkv_b + (size_t)(c + row) * QKV_OUT + HID + kvh * D_;
            u16x8 va = *(const u16x8*)(kr + d0);
            u16x8 vb = *(const u16x8*)(kr + (d0 ^ 64));
            const float* cb = cosb + (size_t)(c + row) * D_ + d0;
            const float* sb = sinb + (size_t)(c + row) * D_ + d0;
            u16x8 ko;
            if (d0 < 64) {
                #pragma unroll
                for (int e = 0; e < 8; ++e)
                    ko[e] = f2bf(bf2f(va[e]) * cb[e] - bf2f(vb[e]) * sb[e]);
            } else {
                #pragma unroll
                for (int e = 0; e < 8; ++e)
                    ko[e] = f2bf(bf2f(va[e]) * cb[e] + bf2f(vb[e]) * sb[e]);
            }
            *(u16x8*)&Kl[row * 136 + d0] = ko;
        }
        // V transposed: thread = 2 rows x 8 dims, packed ds_write_b32 (no rope on V)
        {
            int r2 = (tid & 15) * 2;
            int d0 = (tid >> 4) * 8;
            const unsigned short* vg = qkv + qkv_b + (size_t)(c + r2) * QKV_OUT + HID + NKV * D_ + kvh * D_ + d0;
            u16x8 va = *(const u16x8*)vg;
            u16x8 vb = *(const u16x8*)(vg + QKV_OUT);
            #pragma unroll
            for (int e = 0; e < 8; ++e) {
                unsigned int pack = (unsigned int)va[e] | ((unsigned int)vb[e] << 16);
                *(unsigned int*)&Vt[(d0 + e) * VSTR + r2] = pack;
            }
        }
        __syncthreads();

        if (c + CH - 1 < rw0 - (WINDOW - 1) || c > rw0 + 15) continue;

        // QK^T: two 16-col tiles
        f32x4 s0 = {}, s1 = {};
        #pragma unroll
        for (int kb = 0; kb < 4; ++kb) {
            bf16x8 b0 = *(const bf16x8*)&Kl[lm * 136 + kb * 32 + quad * 8];
            bf16x8 b1 = *(const bf16x8*)&Kl[(16 + lm) * 136 + kb * 32 + quad * 8];
            s0 = __builtin_amdgcn_mfma_f32_16x16x32_bf16(qf[kb], b0, s0, 0, 0, 0);
            s1 = __builtin_amdgcn_mfma_f32_16x16x32_bf16(qf[kb], b1, s1, 0, 0, 0);
        }

        const int j0 = c + lm, j1 = c + 16 + lm;
        float alpha[4];
        #pragma unroll
        for (int r = 0; r < 4; ++r) {
            int row = rw0 + quad * 4 + r;
            float t0 = (j0 <= row && row - j0 < WINDOW) ? s0[r] : -3.0e38f;
            float t1 = (j1 <= row && row - j1 < WINDOW) ? s1[r] : -3.0e38f;
            float cm = fmaxf(t0, t1);
            #pragma unroll
            for (int o = 8; o >= 1; o >>= 1) cm = fmaxf(cm, __shfl_xor(cm, o, 16));
            float mnew = fmaxf(mrow[r], cm);
            float al   = exp2f((mrow[r] - mnew) * SCL);
            float p0   = exp2f((t0 - mnew) * SCL);
            float p1   = exp2f((t1 - mnew) * SCL);
            float rs   = p0 + p1;
            #pragma unroll
            for (int o = 8; o >= 1; o >>= 1) rs += __shfl_xor(rs, o, 16);
            mrow[r] = mnew;
            lrow[r] = lrow[r] * al + rs;
            alpha[r] = al;
            Pl[wave][(quad * 4 + r) * 40 + lm]      = f2bf(p0);
            Pl[wave][(quad * 4 + r) * 40 + 16 + lm] = f2bf(p1);
        }

        #pragma unroll
        for (int nt = 0; nt < 8; ++nt)
            #pragma unroll
            for (int r = 0; r < 4; ++r)
                O[nt][r] *= alpha[r];

        // PV: A = P (wave-private LDS), B = transposed V via ds_read_b128
        bf16x8 pa = *(const bf16x8*)&Pl[wave][lm * 40 + quad * 8];
        #pragma unroll
        for (int nt = 0; nt < 8; ++nt) {
            bf16x8 vbf = *(const bf16x8*)&Vt[(nt * 16 + lm) * VSTR + quad * 8];
            O[nt] = __builtin_amdgcn_mfma_f32_16x16x32_bf16(pa, vbf, O[nt], 0, 0, 0);
        }
    }

    float il[4];
    #pragma unroll
    for (int r = 0; r < 4; ++r) il[r] = 1.0f / lrow[r];
    #pragma unroll
    for (int nt = 0; nt < 8; ++nt)
        #pragma unroll
        for (int r = 0; r < 4; ++r) {
            int row = rw0 + quad * 4 + r;
            attn[(size_t)(b * S_ + row) * (NH * D_) + h * D_ + nt * 16 + lm] = f2bf(O[nt][r] * il[r]);
        }
}

extern "C" void kernel_launch(void* const* d_in, const int* in_sizes, int n_in,
                              void* d_out, int out_size, void* d_ws, size_t ws_size,
                              hipStream_t stream)
{
    const float* hidden = (const float*)d_in[0];
    const float* cosb   = (const float*)d_in[1];
    const float* sinb   = (const float*)d_in[2];
    const float* w_qkv  = (const float*)d_in[3];
    const float* b_qkv  = (const float*)d_in[4];
    const float* w_o    = (const float*)d_in[5];
    const float* b_o    = (const float*)d_in[6];
    float* out = (float*)d_out;

    unsigned char* ws = (unsigned char*)d_ws;
    const size_t QKV_B  = (size_t)M_TOT * QKV_OUT * 2;       // 25.2 MB
    const size_t ATTN_B = (size_t)M_TOT * HID * 2;           // 16.8 MB
    const size_t HB_B   = (size_t)M_TOT * HID * 2;           // 16.8 MB
    const size_t WQ_B   = (size_t)QKV_OUT * HID * 2;         // 50.3 MB
    const size_t WO_B   = (size_t)HID * HID * 2;             // 33.6 MB
    const size_t NEED   = QKV_B + ATTN_B + HB_B + WQ_B;      // aliased-wo layout
    const size_t NEED2  = NEED + WO_B;                        // separate-wo layout

    unsigned short* qkv_ws  = (unsigned short*)(ws);
    unsigned short* attn_ws = (unsigned short*)(ws + QKV_B);

    dim3 blk(256);
    int n8h = M_TOT * HID / 8;
    int n8q = QKV_OUT * HID / 8;
    int n8o = HID * HID / 8;

    if (ws_size >= NEED2) {
        // fused path: 4 launches total
        unsigned short* hb = (unsigned short*)(ws + QKV_B + ATTN_B);
        unsigned short* wq = (unsigned short*)(ws + QKV_B + ATTN_B + HB_B);
        unsigned short* wo = (unsigned short*)(ws + QKV_B + ATTN_B + HB_B + WQ_B);

        conv3_f32_bf16<<<dim3((n8h + n8q + n8o) / 256), blk, 0, stream>>>(
            hidden, hb, n8h, w_qkv, wq, n8q, w_o, wo, n8o);
        gemm256_8ph<3, true><<<dim3(QKV_OUT / 192, M_TOT / 256), dim3(512), 0, stream>>>(
            hb, wq, b_qkv, qkv_ws, M_TOT, QKV_OUT, HID);
        attn_mfma<<<dim3(S_ / 64, NH, B_), blk, 0, stream>>>(qkv_ws, cosb, sinb, attn_ws);
        gemm256_8ph<2, false><<<dim3(HID / 128, M_TOT / 256), dim3(512), 0, stream>>>(
            attn_ws, wo, b_o, out, M_TOT, HID, NH * D_);
    } else if (ws_size >= NEED && WO_B <= HB_B + WQ_B) {
        // r8 layout: wo aliases hb+wq region after gemm1
        unsigned short* hb = (unsigned short*)(ws + QKV_B + ATTN_B);
        unsigned short* wq = (unsigned short*)(ws + QKV_B + ATTN_B + HB_B);
        unsigned short* wo = (unsigned short*)(ws + QKV_B + ATTN_B);

        conv_f32_bf16<<<dim3((n8h + 255) / 256), blk, 0, stream>>>(hidden, hb, n8h);
        conv_f32_bf16<<<dim3((n8q + 255) / 256), blk, 0, stream>>>(w_qkv, wq, n8q);
        gemm256_8ph<3, true><<<dim3(QKV_OUT / 192, M_TOT / 256), dim3(512), 0, stream>>>(
            hb, wq, b_qkv, qkv_ws, M_TOT, QKV_OUT, HID);
        conv_f32_bf16<<<dim3((n8o + 255) / 256), blk, 0, stream>>>(w_o, wo, n8o);
        attn_mfma<<<dim3(S_ / 64, NH, B_), blk, 0, stream>>>(qkv_ws, cosb, sinb, attn_ws);
        gemm256_8ph<2, false><<<dim3(HID / 128, M_TOT / 256), dim3(512), 0, stream>>>(
            attn_ws, wo, b_o, out, M_TOT, HID, NH * D_);
    } else {
        gemm_bt_bias<false, true><<<dim3(QKV_OUT / 128, M_TOT / 128), blk, 0, stream>>>(
            hidden, w_qkv, b_qkv, qkv_ws, M_TOT, QKV_OUT, HID);
        attn_mfma<<<dim3(S_ / 64, NH, B_), blk, 0, stream>>>(qkv_ws, cosb, sinb, attn_ws);
        gemm_bt_bias<true, false><<<dim3(HID / 128, M_TOT / 128), blk, 0, stream>>>(
            attn_ws, w_o, b_o, out, M_TOT, HID, NH * D_);
    }
}

// Round 10
// 494.082 us; speedup vs baseline: 1.0992x; 1.0992x over previous
//
#include <hip/hip_runtime.h>
#include <hip/hip_bf16.h>

#define B_      2
#define S_      1024
#define HID     4096
#define NH      32
#define NKV     8
#define D_      128
#define G_      4
#define WINDOW  512
#define QKV_OUT 6144      // (NH + 2*NKV) * D
#define M_TOT   2048      // B * S
#define CH      32        // kv chunk length in attention
#define VSTR    40        // transposed-V row stride (80 B: 16B-aligned frags, 2-way banks)

typedef __bf16 bf16x8 __attribute__((ext_vector_type(8)));
typedef float  f32x4  __attribute__((ext_vector_type(4)));
typedef unsigned short u16x8 __attribute__((ext_vector_type(8)));

#define AS1 __attribute__((address_space(1)))
#define AS3 __attribute__((address_space(3)))

static __device__ __forceinline__ float bf2f(unsigned short u) {
    union { unsigned int i; float f; } v; v.i = ((unsigned int)u) << 16; return v.f;
}
static __device__ __forceinline__ unsigned short f2bf(float f) {
    union { float f; unsigned int i; } v; v.f = f;
    unsigned int x = v.i;
    return (unsigned short)((x + 0x7fffu + ((x >> 16) & 1u)) >> 16);
}
static __device__ __forceinline__ void gl2lds16(const void* g, void* l) {
    __builtin_amdgcn_global_load_lds((const AS1 void*)g, (AS3 void*)l, 16, 0, 0);
}

// ---------------- fp32 -> bf16 bulk conversion (RTNE) ----------------
__global__ __launch_bounds__(256)
void conv_f32_bf16(const float* __restrict__ src, unsigned short* __restrict__ dst, int n8)
{
    int i = blockIdx.x * 256 + threadIdx.x;
    if (i >= n8) return;
    const float* p = src + (size_t)i * 8;
    float4 f0 = *(const float4*)p;
    float4 f1 = *(const float4*)(p + 4);
    u16x8 h;
    h[0]=f2bf(f0.x); h[1]=f2bf(f0.y); h[2]=f2bf(f0.z); h[3]=f2bf(f0.w);
    h[4]=f2bf(f1.x); h[5]=f2bf(f1.y); h[6]=f2bf(f1.z); h[7]=f2bf(f1.w);
    *(u16x8*)&dst[(size_t)i * 8] = h;
}

// ---------------- fused 3-tensor fp32 -> bf16 conversion (one launch) ----------------
// n8h/n8q/n8o are all multiples of 256 -> branch is block-uniform.
__global__ __launch_bounds__(256)
void conv3_f32_bf16(const float* __restrict__ s0, unsigned short* __restrict__ d0, int n0,
                    const float* __restrict__ s1, unsigned short* __restrict__ d1, int n1,
                    const float* __restrict__ s2, unsigned short* __restrict__ d2, int n2)
{
    int i = blockIdx.x * 256 + threadIdx.x;
    const float* s; unsigned short* d;
    if (i < n0)                { s = s0; d = d0; }
    else if ((i -= n0) < n1)   { s = s1; d = d1; }
    else if ((i -= n1) < n2)   { s = s2; d = d2; }
    else return;
    const float* p = s + (size_t)i * 8;
    float4 f0 = *(const float4*)p;
    float4 f1 = *(const float4*)(p + 4);
    u16x8 h;
    h[0]=f2bf(f0.x); h[1]=f2bf(f0.y); h[2]=f2bf(f0.z); h[3]=f2bf(f0.w);
    h[4]=f2bf(f1.x); h[5]=f2bf(f1.y); h[6]=f2bf(f1.z); h[7]=f2bf(f1.w);
    *(u16x8*)&d[(size_t)i * 8] = h;
}

// ---------------- K-only RoPE (in-place on bf16 qkv) ----------------
// r9 lesson: K-rope fused into attn's chunk loop was recomputed ~70x
// (per Q-block x per head sharing the KV head) -> attn 95->165us.  Rope
// must be once-per-element: Q-rope stays fused in attn (each Q[row,h] is
// read by exactly ONE block -> zero redundancy); K-rope is this tiny
// kernel (NKV=8 heads, 1/5 of the old all-head rope's traffic).
__global__ __launch_bounds__(256)
void rope_k_kernel(unsigned short* __restrict__ qkv,
                   const float* __restrict__ cosb,
                   const float* __restrict__ sinb)
{
    int t    = blockIdx.x * 256 + threadIdx.x;   // M_TOT * NKV * 64 threads
    int d    = t & 63;
    int rest = t >> 6;
    int head = rest & (NKV - 1);
    int m    = rest >> 3;                        // NKV == 8
    int s    = m & (S_ - 1);
    size_t base = (size_t)m * QKV_OUT + HID + head * D_;

    float x1 = bf2f(qkv[base + d]);
    float x2 = bf2f(qkv[base + d + 64]);
    float c1 = cosb[s * D_ + d];
    float s1 = sinb[s * D_ + d];
    float c2 = cosb[s * D_ + d + 64];
    float s2 = sinb[s * D_ + d + 64];
    qkv[base + d]      = f2bf(x1 * c1 - x2 * s1);
    qkv[base + d + 64] = f2bf(x2 * c2 + x1 * s2);
}

// ================= 256 x (NT*64) 4-phase pipelined GEMM =================
// r8-proven (passing, QKV 105us @ MfmaUtil 41 / 0 conflicts; O-proj < 105us).
// UNCHANGED -- control.  Full design notes in r8.
#define MFMA_CL(MT0, MT1, AR)                                                          \
    __builtin_amdgcn_s_setprio(1);                                                     \
    _Pragma("unroll")                                                                  \
    for (int ks = 0; ks < 2; ++ks) {                                                   \
        _Pragma("unroll")                                                              \
        for (int nt = 0; nt < NT; ++nt) {                                              \
            acc[MT0][nt] = __builtin_amdgcn_mfma_f32_16x16x32_bf16(AR[0][ks], bC[nt][ks], acc[MT0][nt], 0, 0, 0); \
            acc[MT1][nt] = __builtin_amdgcn_mfma_f32_16x16x32_bf16(AR[1][ks], bC[nt][ks], acc[MT1][nt], 0, 0, 0); \
        }                                                                              \
    }                                                                                  \
    __builtin_amdgcn_s_setprio(0);

#define SCHED __builtin_amdgcn_sched_barrier(0)
#define WAITLGKM(N) do { asm volatile("s_waitcnt lgkmcnt(" #N ")" ::: "memory"); SCHED; } while (0)
#define WAITVM_STEADY do {                                                             \
    if constexpr (NT == 3) { asm volatile("s_waitcnt vmcnt(5)" ::: "memory"); }        \
    else                   { asm volatile("s_waitcnt vmcnt(4)" ::: "memory"); }        \
} while (0)
#define BARRIER do { SCHED; __builtin_amdgcn_s_barrier(); SCHED; } while (0)

template<int NT, bool C_BF16>
__global__ __launch_bounds__(512, 2)
void gemm256_8ph(const unsigned short* __restrict__ A,
                 const unsigned short* __restrict__ Bw,
                 const float* __restrict__ bias,
                 void* __restrict__ Cv,
                 int M, int N, int K)
{
    __shared__ __attribute__((aligned(1024))) unsigned short lds[32768 + NT * 8192];

    const int tid  = threadIdx.x;
    const int lane = tid & 63;
    const int w    = tid >> 6;        // 0..7
    const int m_   = w >> 2;          // 0..1  (M half, 128 rows)
    const int n_   = w & 3;           // 0..3  (N quarter, NT*16 cols)
    const int lm   = lane & 15, quad = lane >> 4;
    const int m0   = blockIdx.y * 256, n0 = blockIdx.x * (NT * 64);
    const int nkt  = K >> 6;          // BK=64 tiles (requires nkt >= 3)

    const int srow = lane >> 3;                  // 0..7 row within 8-row instr
    const int scol = ((lane & 7) ^ srow) * 8;    // elem col within BK=64 (inverse swizzle)

    const int arow0 = m0 + m_ * 128 + n_ * 16;   // staged A rows n_*16..+15
    const int arow1 = arow0 + 64;                // staged A rows 64+n_*16..+15
    const int brow  = n0 + w * (NT * 8);         // staged B rows, NT*8 per wave

    const int ldsAr = m_ * 8192;                            // A read base (own half)
    const int ldsA0 = ldsAr + n_ * 1024;                    // A stage rp0
    const int ldsA1 = ldsA0 + 4096;                         // A stage rp1
    const int ldsBs = 32768 + w * (NT * 512);               // B stage base
    const int ldsBr = 32768 + n_ * (NT * 1024);             // B read base

    f32x4 acc[8][NT] = {};
    bf16x8 bC[NT][2];          // B frags, whole tile (read at tile boundary)
    bf16x8 aP[2][2], aQ[2][2]; // A frag ping-pong (one phase ahead)

    auto stA = [&](int T, int rp) {
        const int k0   = T << 6;
        const int bufo = (T & 1) << 14;
        const int rb   = (rp ? arow1 : arow0) + srow;
        const int lb   = (rp ? ldsA1 : ldsA0) + bufo + lane * 8;
        gl2lds16(&A[(size_t)rb * K + k0 + scol],       &lds[lb]);
        gl2lds16(&A[(size_t)(rb + 8) * K + k0 + scol], &lds[lb + 512]);
    };
    auto stB = [&](int T, int pr) {   // pr0: first NT-1 loads, pr1: last 8 rows (1 load)
        const int k0   = T << 6;
        const int bufo = (T & 1) * (NT * 4096);
        if (pr == 0) {
            #pragma unroll
            for (int j = 0; j < NT - 1; ++j) {
                const int rb = brow + j * 8 + srow;
                gl2lds16(&Bw[(size_t)rb * K + k0 + scol],
                         &lds[ldsBs + j * 512 + bufo + lane * 8]);
            }
        } else {
            const int rb = brow + (NT - 1) * 8 + srow;
            gl2lds16(&Bw[(size_t)rb * K + k0 + scol],
                     &lds[ldsBs + (NT - 1) * 512 + bufo + lane * 8]);
        }
    };
    auto rdA = [&](int T, int mt, int ks) -> bf16x8 {
        int e = (mt * 16 + lm) * 64 + ks * 32 + quad * 8;
        e ^= ((e >> 6) & 7) << 3;                 // slot ^= row&7 (conflict-free)
        return *(const bf16x8*)&lds[((T & 1) << 14) + ldsAr + e];
    };
    auto rdB = [&](int T, int nt, int ks) -> bf16x8 {
        int e = (nt * 16 + lm) * 64 + ks * 32 + quad * 8;
        e ^= ((e >> 6) & 7) << 3;                 // all bases 512-elem mult: bits 6-8 clean
        return *(const bf16x8*)&lds[(T & 1) * (NT * 4096) + ldsBr + e];
    };
    auto rdBoundary = [&](int T) {
        #pragma unroll
        for (int nt = 0; nt < NT; ++nt)
            #pragma unroll
            for (int ks = 0; ks < 2; ++ks) bC[nt][ks] = rdB(T, nt, ks);
        #pragma unroll
        for (int ks = 0; ks < 2; ++ks) { aP[0][ks] = rdA(T, 0, ks); aP[1][ks] = rdA(T, 1, ks); }
    };

    // prologue: tile0 full (NT+4 loads) + tile1 first NT+2; drain tile0
    stB(0, 0); stB(0, 1); stA(0, 0); stA(0, 1);
    stB(1, 0); stB(1, 1); stA(1, 0);
    WAITVM_STEADY;
    BARRIER;
    rdBoundary(0);
    SCHED;

    #pragma unroll 1
    for (int i = 0; i < nkt; ++i) {
        // ---- P1: MFMA mt0,1 (aP); prefetch mt2,3 -> aQ ----
        if (i + 1 < nkt) stA(i + 1, 1);
        #pragma unroll
        for (int ks = 0; ks < 2; ++ks) { aQ[0][ks] = rdA(i, 2, ks); aQ[1][ks] = rdA(i, 3, ks); }
        SCHED;
        WAITLGKM(4);          // drains boundary (2NT+4); leaves aQ's 4
        MFMA_CL(0, 1, aP)
        BARRIER;
        // ---- P2: MFMA mt2,3 (aQ); prefetch mt4,5 -> aP ----  (no end barrier)
        if (i + 2 < nkt) stB(i + 2, 0);
        #pragma unroll
        for (int ks = 0; ks < 2; ++ks) { aP[0][ks] = rdA(i, 4, ks); aP[1][ks] = rdA(i, 5, ks); }
        SCHED;
        WAITLGKM(4);          // drains aQ's 4; leaves aP's 4
        MFMA_CL(2, 3, aQ)
        // ---- P3: MFMA mt4,5 (aP); prefetch mt6,7 -> aQ ----  (no end barrier)
        if (i + 2 < nkt) stB(i + 2, 1);
        #pragma unroll
        for (int ks = 0; ks < 2; ++ks) { aQ[0][ks] = rdA(i, 6, ks); aQ[1][ks] = rdA(i, 7, ks); }
        SCHED;
        WAITLGKM(4);
        MFMA_CL(4, 5, aP)
        // ---- P4: MFMA mt6,7 (aQ); boundary vmcnt; boundary reads for i+1 ----
        if (i + 2 < nkt) stA(i + 2, 0);
        SCHED;
        WAITLGKM(0);          // drains aQ's 4 (only lgkm outstanding)
        MFMA_CL(6, 7, aQ)
        SCHED;
        if (i + 2 < nkt)      { WAITVM_STEADY; }
        else if (i + 1 < nkt) { asm volatile("s_waitcnt vmcnt(0)" ::: "memory"); }
        BARRIER;
        if (i + 1 < nkt) rdBoundary(i + 1);
        SCHED;
    }

    #pragma unroll
    for (int nt = 0; nt < NT; ++nt) {
        const int col = n0 + n_ * (NT * 16) + nt * 16 + lm;
        const float bv = bias[col];
        #pragma unroll
        for (int mt = 0; mt < 8; ++mt) {
            const int rowb = m0 + m_ * 128 + mt * 16 + quad * 4;
            #pragma unroll
            for (int r = 0; r < 4; ++r) {
                const float val = acc[mt][nt][r] + bv;
                if (C_BF16)
                    ((unsigned short*)Cv)[(size_t)(rowb + r) * N + col] = f2bf(val);
                else
                    ((float*)Cv)[(size_t)(rowb + r) * N + col] = val;
            }
        }
    }
}

// ---------------- fallback GEMM (fp32 staging, round-3 proven) ----------------
template<bool A_BF16, bool C_BF16>
__global__ __launch_bounds__(256)
void gemm_bt_bias(const void* __restrict__ Av,
                  const float* __restrict__ Bw,
                  const float* __restrict__ bias,
                  void* __restrict__ Cv,
                  int M, int N, int K)
{
    __shared__ unsigned short As[128 * 40];
    __shared__ unsigned short Bs[128 * 40];

    const int tid  = threadIdx.x;
    const int m0   = blockIdx.y * 128;
    const int n0   = blockIdx.x * 128;
    const int wave = tid >> 6, lane = tid & 63;
    const int wm   = (wave >> 1) * 64;
    const int wn   = (wave & 1) * 64;
    const int lm   = lane & 15, quad = lane >> 4;

    f32x4 acc[4][4] = {};

    for (int k0 = 0; k0 < K; k0 += 32) {
        __syncthreads();
        #pragma unroll
        for (int c = 0; c < 2; ++c) {
            int chunk = tid + c * 256;
            int row   = chunk >> 2;
            int off   = (chunk & 3) * 8;
            if (A_BF16) {
                *(u16x8*)&As[row * 40 + off] =
                    *(const u16x8*)&((const unsigned short*)Av)[(size_t)(m0 + row) * K + k0 + off];
            } else {
                const float* ap = &((const float*)Av)[(size_t)(m0 + row) * K + k0 + off];
                float4 f0 = *(const float4*)ap;
                float4 f1 = *(const float4*)(ap + 4);
                u16x8 h;
                h[0]=f2bf(f0.x); h[1]=f2bf(f0.y); h[2]=f2bf(f0.z); h[3]=f2bf(f0.w);
                h[4]=f2bf(f1.x); h[5]=f2bf(f1.y); h[6]=f2bf(f1.z); h[7]=f2bf(f1.w);
                *(u16x8*)&As[row * 40 + off] = h;
            }
            {
                const float* bp = &Bw[(size_t)(n0 + row) * K + k0 + off];
                float4 f0 = *(const float4*)bp;
                float4 f1 = *(const float4*)(bp + 4);
                u16x8 h;
                h[0]=f2bf(f0.x); h[1]=f2bf(f0.y); h[2]=f2bf(f0.z); h[3]=f2bf(f0.w);
                h[4]=f2bf(f1.x); h[5]=f2bf(f1.y); h[6]=f2bf(f1.z); h[7]=f2bf(f1.w);
                *(u16x8*)&Bs[row * 40 + off] = h;
            }
        }
        __syncthreads();

        bf16x8 afr[4], bfr[4];
        #pragma unroll
        for (int i = 0; i < 4; ++i)
            afr[i] = *(const bf16x8*)&As[(wm + i * 16 + lm) * 40 + quad * 8];
        #pragma unroll
        for (int j = 0; j < 4; ++j)
            bfr[j] = *(const bf16x8*)&Bs[(wn + j * 16 + lm) * 40 + quad * 8];

        #pragma unroll
        for (int i = 0; i < 4; ++i)
            #pragma unroll
            for (int j = 0; j < 4; ++j)
                acc[i][j] = __builtin_amdgcn_mfma_f32_16x16x32_bf16(afr[i], bfr[j], acc[i][j], 0, 0, 0);
    }

    #pragma unroll
    for (int j = 0; j < 4; ++j) {
        int col = n0 + wn + j * 16 + lm;
        float bv = bias[col];
        #pragma unroll
        for (int i = 0; i < 4; ++i) {
            int rowb = m0 + wm + i * 16 + quad * 4;
            #pragma unroll
            for (int r = 0; r < 4; ++r) {
                float val = acc[i][j][r] + bv;
                if (C_BF16)
                    ((unsigned short*)Cv)[(size_t)(rowb + r) * N + col] = f2bf(val);
                else
                    ((float*)Cv)[(size_t)(rowb + r) * N + col] = val;
            }
        }
    }
}

// ---------------- Flash-style MFMA attention with fused Q-RoPE ----------------
// r9 -> r10: K-rope moved OUT of the chunk loop (to rope_k_kernel -- it was
// recomputed ~70x per element when fused, attn 95->165us).  Q-rope stays
// fused (once per block, zero redundancy, r9-proven numerics).  K staging
// reverted to the r8 plain 16B/lane copy; qkv holds rope'd K on entry.
__global__ __launch_bounds__(256)
void attn_mfma(const unsigned short* __restrict__ qkv,
               const float* __restrict__ cosb,
               const float* __restrict__ sinb,
               unsigned short* __restrict__ attn)
{
    __shared__ unsigned short Kl[CH * 136];
    __shared__ unsigned short Vt[128 * VSTR];    // [dim][row] transposed
    __shared__ unsigned short Pl[4][16 * 40];

    const int tid  = threadIdx.x;
    const int wave = tid >> 6, lane = tid & 63;
    const int lm   = lane & 15, quad = lane >> 4;
    const int h    = blockIdx.y;
    const int b    = blockIdx.z;
    const int kvh  = h >> 2;
    const int r0b  = blockIdx.x * 64;
    const int rw0  = r0b + wave * 16;

    const size_t qkv_b = (size_t)b * S_ * QKV_OUT;
    const float SCL = 0.12751974f;   // (1/sqrt(128)) * log2(e)

    // Q load + in-register rope (d <-> d+64 pair is qf[kb] <-> qf[kb+2],
    // same lane: d+64 = (kb+2)*32 + quad*8 + e)
    bf16x8 qf[4];
    {
        const unsigned short* qrow = qkv + qkv_b + (size_t)(rw0 + lm) * QKV_OUT + h * D_ + quad * 8;
        u16x8 qr[4];
        #pragma unroll
        for (int kb = 0; kb < 4; ++kb)
            qr[kb] = *(const u16x8*)(qrow + kb * 32);
        const float* cb = cosb + (size_t)(rw0 + lm) * D_ + quad * 8;
        const float* sb = sinb + (size_t)(rw0 + lm) * D_ + quad * 8;
        u16x8 qo[4];
        #pragma unroll
        for (int kb = 0; kb < 2; ++kb)
            #pragma unroll
            for (int e = 0; e < 8; ++e) {
                int d = kb * 32 + e;
                float x1 = bf2f(qr[kb][e]);
                float x2 = bf2f(qr[kb + 2][e]);
                qo[kb][e]     = f2bf(x1 * cb[d]      - x2 * sb[d]);
                qo[kb + 2][e] = f2bf(x2 * cb[d + 64] + x1 * sb[d + 64]);
            }
        #pragma unroll
        for (int kb = 0; kb < 4; ++kb)
            qf[kb] = *(const bf16x8*)&qo[kb];
    }

    f32x4 O[8] = {};
    float mrow[4] = {-1e30f, -1e30f, -1e30f, -1e30f};
    float lrow[4] = {0.f, 0.f, 0.f, 0.f};

    const int c0   = max(0, r0b - (WINDOW - 1)) & ~(CH - 1);
    const int cend = r0b + 64 - CH;

    for (int c = c0; c <= cend; c += CH) {
        __syncthreads();
        // K: rows c..c+31 (already rope'd by rope_k_kernel), 16B/lane copy
        #pragma unroll
        for (int p = 0; p < 2; ++p) {
            int idx = tid + p * 256;
            int row = idx >> 4;
            int d0  = (idx & 15) * 8;
            *(u16x8*)&Kl[row * 136 + d0] =
                *(const u16x8*)(qkv + qkv_b + (size_t)(c + row) * QKV_OUT + HID + kvh * D_ + d0);
        }
        // V transposed: thread = 2 rows x 8 dims, packed ds_write_b32 (no rope on V)
        {
            int r2 = (tid & 15) * 2;
            int d0 = (tid >> 4) * 8;
            const unsigned short* vg = qkv + qkv_b + (size_t)(c + r2) * QKV_OUT + HID + NKV * D_ + kvh * D_ + d0;
            u16x8 va = *(const u16x8*)vg;
            u16x8 vb = *(const u16x8*)(vg + QKV_OUT);
            #pragma unroll
            for (int e = 0; e < 8; ++e) {
                unsigned int pack = (unsigned int)va[e] | ((unsigned int)vb[e] << 16);
                *(unsigned int*)&Vt[(d0 + e) * VSTR + r2] = pack;
            }
        }
        __syncthreads();

        if (c + CH - 1 < rw0 - (WINDOW - 1) || c > rw0 + 15) continue;

        // QK^T: two 16-col tiles
        f32x4 s0 = {}, s1 = {};
        #pragma unroll
        for (int kb = 0; kb < 4; ++kb) {
            bf16x8 b0 = *(const bf16x8*)&Kl[lm * 136 + kb * 32 + quad * 8];
            bf16x8 b1 = *(const bf16x8*)&Kl[(16 + lm) * 136 + kb * 32 + quad * 8];
            s0 = __builtin_amdgcn_mfma_f32_16x16x32_bf16(qf[kb], b0, s0, 0, 0, 0);
            s1 = __builtin_amdgcn_mfma_f32_16x16x32_bf16(qf[kb], b1, s1, 0, 0, 0);
        }

        const int j0 = c + lm, j1 = c + 16 + lm;
        float alpha[4];
        #pragma unroll
        for (int r = 0; r < 4; ++r) {
            int row = rw0 + quad * 4 + r;
            float t0 = (j0 <= row && row - j0 < WINDOW) ? s0[r] : -3.0e38f;
            float t1 = (j1 <= row && row - j1 < WINDOW) ? s1[r] : -3.0e38f;
            float cm = fmaxf(t0, t1);
            #pragma unroll
            for (int o = 8; o >= 1; o >>= 1) cm = fmaxf(cm, __shfl_xor(cm, o, 16));
            float mnew = fmaxf(mrow[r], cm);
            float al   = exp2f((mrow[r] - mnew) * SCL);
            float p0   = exp2f((t0 - mnew) * SCL);
            float p1   = exp2f((t1 - mnew) * SCL);
            float rs   = p0 + p1;
            #pragma unroll
            for (int o = 8; o >= 1; o >>= 1) rs += __shfl_xor(rs, o, 16);
            mrow[r] = mnew;
            lrow[r] = lrow[r] * al + rs;
            alpha[r] = al;
            Pl[wave][(quad * 4 + r) * 40 + lm]      = f2bf(p0);
            Pl[wave][(quad * 4 + r) * 40 + 16 + lm] = f2bf(p1);
        }

        #pragma unroll
        for (int nt = 0; nt < 8; ++nt)
            #pragma unroll
            for (int r = 0; r < 4; ++r)
                O[nt][r] *= alpha[r];

        // PV: A = P (wave-private LDS), B = transposed V via ds_read_b128
        bf16x8 pa = *(const bf16x8*)&Pl[wave][lm * 40 + quad * 8];
        #pragma unroll
        for (int nt = 0; nt < 8; ++nt) {
            bf16x8 vbf = *(const bf16x8*)&Vt[(nt * 16 + lm) * VSTR + quad * 8];
            O[nt] = __builtin_amdgcn_mfma_f32_16x16x32_bf16(pa, vbf, O[nt], 0, 0, 0);
        }
    }

    float il[4];
    #pragma unroll
    for (int r = 0; r < 4; ++r) il[r] = 1.0f / lrow[r];
    #pragma unroll
    for (int nt = 0; nt < 8; ++nt)
        #pragma unroll
        for (int r = 0; r < 4; ++r) {
            int row = rw0 + quad * 4 + r;
            attn[(size_t)(b * S_ + row) * (NH * D_) + h * D_ + nt * 16 + lm] = f2bf(O[nt][r] * il[r]);
        }
}

extern "C" void kernel_launch(void* const* d_in, const int* in_sizes, int n_in,
                              void* d_out, int out_size, void* d_ws, size_t ws_size,
                              hipStream_t stream)
{
    const float* hidden = (const float*)d_in[0];
    const float* cosb   = (const float*)d_in[1];
    const float* sinb   = (const float*)d_in[2];
    const float* w_qkv  = (const float*)d_in[3];
    const float* b_qkv  = (const float*)d_in[4];
    const float* w_o    = (const float*)d_in[5];
    const float* b_o    = (const float*)d_in[6];
    float* out = (float*)d_out;

    unsigned char* ws = (unsigned char*)d_ws;
    const size_t QKV_B  = (size_t)M_TOT * QKV_OUT * 2;       // 25.2 MB
    const size_t ATTN_B = (size_t)M_TOT * HID * 2;           // 16.8 MB
    const size_t HB_B   = (size_t)M_TOT * HID * 2;           // 16.8 MB
    const size_t WQ_B   = (size_t)QKV_OUT * HID * 2;         // 50.3 MB
    const size_t WO_B   = (size_t)HID * HID * 2;             // 33.6 MB
    const size_t NEED   = QKV_B + ATTN_B + HB_B + WQ_B;      // aliased-wo layout
    const size_t NEED2  = NEED + WO_B;                        // separate-wo layout

    unsigned short* qkv_ws  = (unsigned short*)(ws);
    unsigned short* attn_ws = (unsigned short*)(ws + QKV_B);

    dim3 blk(256);
    int n8h = M_TOT * HID / 8;
    int n8q = QKV_OUT * HID / 8;
    int n8o = HID * HID / 8;
    const int ropek_blocks = (M_TOT * NKV * 64) / 256;

    if (ws_size >= NEED2) {
        // fused path: 5 launches total
        unsigned short* hb = (unsigned short*)(ws + QKV_B + ATTN_B);
        unsigned short* wq = (unsigned short*)(ws + QKV_B + ATTN_B + HB_B);
        unsigned short* wo = (unsigned short*)(ws + QKV_B + ATTN_B + HB_B + WQ_B);

        conv3_f32_bf16<<<dim3((n8h + n8q + n8o) / 256), blk, 0, stream>>>(
            hidden, hb, n8h, w_qkv, wq, n8q, w_o, wo, n8o);
        gemm256_8ph<3, true><<<dim3(QKV_OUT / 192, M_TOT / 256), dim3(512), 0, stream>>>(
            hb, wq, b_qkv, qkv_ws, M_TOT, QKV_OUT, HID);
        rope_k_kernel<<<dim3(ropek_blocks), blk, 0, stream>>>(qkv_ws, cosb, sinb);
        attn_mfma<<<dim3(S_ / 64, NH, B_), blk, 0, stream>>>(qkv_ws, cosb, sinb, attn_ws);
        gemm256_8ph<2, false><<<dim3(HID / 128, M_TOT / 256), dim3(512), 0, stream>>>(
            attn_ws, wo, b_o, out, M_TOT, HID, NH * D_);
    } else if (ws_size >= NEED && WO_B <= HB_B + WQ_B) {
        // r8 layout: wo aliases hb+wq region after gemm1
        unsigned short* hb = (unsigned short*)(ws + QKV_B + ATTN_B);
        unsigned short* wq = (unsigned short*)(ws + QKV_B + ATTN_B + HB_B);
        unsigned short* wo = (unsigned short*)(ws + QKV_B + ATTN_B);

        conv_f32_bf16<<<dim3((n8h + 255) / 256), blk, 0, stream>>>(hidden, hb, n8h);
        conv_f32_bf16<<<dim3((n8q + 255) / 256), blk, 0, stream>>>(w_qkv, wq, n8q);
        gemm256_8ph<3, true><<<dim3(QKV_OUT / 192, M_TOT / 256), dim3(512), 0, stream>>>(
            hb, wq, b_qkv, qkv_ws, M_TOT, QKV_OUT, HID);
        conv_f32_bf16<<<dim3((n8o + 255) / 256), blk, 0, stream>>>(w_o, wo, n8o);
        rope_k_kernel<<<dim3(ropek_blocks), blk, 0, stream>>>(qkv_ws, cosb, sinb);
        attn_mfma<<<dim3(S_ / 64, NH, B_), blk, 0, stream>>>(qkv_ws, cosb, sinb, attn_ws);
        gemm256_8ph<2, false><<<dim3(HID / 128, M_TOT / 256), dim3(512), 0, stream>>>(
            attn_ws, wo, b_o, out, M_TOT, HID, NH * D_);
    } else {
        gemm_bt_bias<false, true><<<dim3(QKV_OUT / 128, M_TOT / 128), blk, 0, stream>>>(
            hidden, w_qkv, b_qkv, qkv_ws, M_TOT, QKV_OUT, HID);
        rope_k_kernel<<<dim3(ropek_blocks), blk, 0, stream>>>(qkv_ws, cosb, sinb);
        attn_mfma<<<dim3(S_ / 64, NH, B_), blk, 0, stream>>>(qkv_ws, cosb, sinb, attn_ws);
        gemm_bt_bias<true, false><<<dim3(HID / 128, M_TOT / 128), blk, 0, stream>>>(
            attn_ws, w_o, b_o, out, M_TOT, HID, NH * D_);
    }
}

// Round 11
// 472.212 us; speedup vs baseline: 1.1501x; 1.0463x over previous
//
#include <hip/hip_runtime.h>
#include <hip/hip_bf16.h>

#define B_      2
#define S_      1024
#define HID     4096
#define NH      32
#define NKV     8
#define D_      128
#define G_      4
#define WINDOW  512
#define QKV_OUT 6144      // (NH + 2*NKV) * D
#define M_TOT   2048      // B * S
#define CH      32        // kv chunk length in attention
#define VSTR    40        // transposed-V row stride (80 B: 16B-aligned frags, 2-way banks)

typedef __bf16 bf16x8 __attribute__((ext_vector_type(8)));
typedef float  f32x4  __attribute__((ext_vector_type(4)));
typedef unsigned short u16x8 __attribute__((ext_vector_type(8)));

#define AS1 __attribute__((address_space(1)))
#define AS3 __attribute__((address_space(3)))

static __device__ __forceinline__ float bf2f(unsigned short u) {
    union { unsigned int i; float f; } v; v.i = ((unsigned int)u) << 16; return v.f;
}
static __device__ __forceinline__ unsigned short f2bf(float f) {
    union { float f; unsigned int i; } v; v.f = f;
    unsigned int x = v.i;
    return (unsigned short)((x + 0x7fffu + ((x >> 16) & 1u)) >> 16);
}
static __device__ __forceinline__ void gl2lds16(const void* g, void* l) {
    __builtin_amdgcn_global_load_lds((const AS1 void*)g, (AS3 void*)l, 16, 0, 0);
}

// ---------------- fp32 -> bf16 bulk conversion (RTNE) ----------------
__global__ __launch_bounds__(256)
void conv_f32_bf16(const float* __restrict__ src, unsigned short* __restrict__ dst, int n8)
{
    int i = blockIdx.x * 256 + threadIdx.x;
    if (i >= n8) return;
    const float* p = src + (size_t)i * 8;
    float4 f0 = *(const float4*)p;
    float4 f1 = *(const float4*)(p + 4);
    u16x8 h;
    h[0]=f2bf(f0.x); h[1]=f2bf(f0.y); h[2]=f2bf(f0.z); h[3]=f2bf(f0.w);
    h[4]=f2bf(f1.x); h[5]=f2bf(f1.y); h[6]=f2bf(f1.z); h[7]=f2bf(f1.w);
    *(u16x8*)&dst[(size_t)i * 8] = h;
}

// ---------------- fused 3-tensor fp32 -> bf16 conversion (one launch) ----------------
// n8h/n8q/n8o are all multiples of 256 -> branch is block-uniform.
__global__ __launch_bounds__(256)
void conv3_f32_bf16(const float* __restrict__ s0, unsigned short* __restrict__ d0, int n0,
                    const float* __restrict__ s1, unsigned short* __restrict__ d1, int n1,
                    const float* __restrict__ s2, unsigned short* __restrict__ d2, int n2)
{
    int i = blockIdx.x * 256 + threadIdx.x;
    const float* s; unsigned short* d;
    if (i < n0)                { s = s0; d = d0; }
    else if ((i -= n0) < n1)   { s = s1; d = d1; }
    else if ((i -= n1) < n2)   { s = s2; d = d2; }
    else return;
    const float* p = s + (size_t)i * 8;
    float4 f0 = *(const float4*)p;
    float4 f1 = *(const float4*)(p + 4);
    u16x8 h;
    h[0]=f2bf(f0.x); h[1]=f2bf(f0.y); h[2]=f2bf(f0.z); h[3]=f2bf(f0.w);
    h[4]=f2bf(f1.x); h[5]=f2bf(f1.y); h[6]=f2bf(f1.z); h[7]=f2bf(f1.w);
    *(u16x8*)&d[(size_t)i * 8] = h;
}

// ---------------- K-only RoPE (in-place on bf16 qkv) ----------------
// Once-per-element (r9 lesson: fusing K-rope into attn's chunk loop
// recomputed it ~70x).  Q-rope stays fused in attn (zero redundancy).
__global__ __launch_bounds__(256)
void rope_k_kernel(unsigned short* __restrict__ qkv,
                   const float* __restrict__ cosb,
                   const float* __restrict__ sinb)
{
    int t    = blockIdx.x * 256 + threadIdx.x;   // M_TOT * NKV * 64 threads
    int d    = t & 63;
    int rest = t >> 6;
    int head = rest & (NKV - 1);
    int m    = rest >> 3;                        // NKV == 8
    int s    = m & (S_ - 1);
    size_t base = (size_t)m * QKV_OUT + HID + head * D_;

    float x1 = bf2f(qkv[base + d]);
    float x2 = bf2f(qkv[base + d + 64]);
    float c1 = cosb[s * D_ + d];
    float s1 = sinb[s * D_ + d];
    float c2 = cosb[s * D_ + d + 64];
    float s2 = sinb[s * D_ + d + 64];
    qkv[base + d]      = f2bf(x1 * c1 - x2 * s1);
    qkv[base + d + 64] = f2bf(x2 * c2 + x1 * s2);
}

// ================= 256 x (NT*64) 4-phase pipelined GEMM =================
// r8-proven (passing, QKV ~104us @ MfmaUtil 42 / 0 conflicts; O-proj < 104us).
// UNCHANGED -- control.  Full design notes in r8.
#define MFMA_CL(MT0, MT1, AR)                                                          \
    __builtin_amdgcn_s_setprio(1);                                                     \
    _Pragma("unroll")                                                                  \
    for (int ks = 0; ks < 2; ++ks) {                                                   \
        _Pragma("unroll")                                                              \
        for (int nt = 0; nt < NT; ++nt) {                                              \
            acc[MT0][nt] = __builtin_amdgcn_mfma_f32_16x16x32_bf16(AR[0][ks], bC[nt][ks], acc[MT0][nt], 0, 0, 0); \
            acc[MT1][nt] = __builtin_amdgcn_mfma_f32_16x16x32_bf16(AR[1][ks], bC[nt][ks], acc[MT1][nt], 0, 0, 0); \
        }                                                                              \
    }                                                                                  \
    __builtin_amdgcn_s_setprio(0);

#define SCHED __builtin_amdgcn_sched_barrier(0)
#define WAITLGKM(N) do { asm volatile("s_waitcnt lgkmcnt(" #N ")" ::: "memory"); SCHED; } while (0)
#define WAITVM_STEADY do {                                                             \
    if constexpr (NT == 3) { asm volatile("s_waitcnt vmcnt(5)" ::: "memory"); }        \
    else                   { asm volatile("s_waitcnt vmcnt(4)" ::: "memory"); }        \
} while (0)
#define BARRIER do { SCHED; __builtin_amdgcn_s_barrier(); SCHED; } while (0)

template<int NT, bool C_BF16>
__global__ __launch_bounds__(512, 2)
void gemm256_8ph(const unsigned short* __restrict__ A,
                 const unsigned short* __restrict__ Bw,
                 const float* __restrict__ bias,
                 void* __restrict__ Cv,
                 int M, int N, int K)
{
    __shared__ __attribute__((aligned(1024))) unsigned short lds[32768 + NT * 8192];

    const int tid  = threadIdx.x;
    const int lane = tid & 63;
    const int w    = tid >> 6;        // 0..7
    const int m_   = w >> 2;          // 0..1  (M half, 128 rows)
    const int n_   = w & 3;           // 0..3  (N quarter, NT*16 cols)
    const int lm   = lane & 15, quad = lane >> 4;
    const int m0   = blockIdx.y * 256, n0 = blockIdx.x * (NT * 64);
    const int nkt  = K >> 6;          // BK=64 tiles (requires nkt >= 3)

    const int srow = lane >> 3;                  // 0..7 row within 8-row instr
    const int scol = ((lane & 7) ^ srow) * 8;    // elem col within BK=64 (inverse swizzle)

    const int arow0 = m0 + m_ * 128 + n_ * 16;   // staged A rows n_*16..+15
    const int arow1 = arow0 + 64;                // staged A rows 64+n_*16..+15
    const int brow  = n0 + w * (NT * 8);         // staged B rows, NT*8 per wave

    const int ldsAr = m_ * 8192;                            // A read base (own half)
    const int ldsA0 = ldsAr + n_ * 1024;                    // A stage rp0
    const int ldsA1 = ldsA0 + 4096;                         // A stage rp1
    const int ldsBs = 32768 + w * (NT * 512);               // B stage base
    const int ldsBr = 32768 + n_ * (NT * 1024);             // B read base

    f32x4 acc[8][NT] = {};
    bf16x8 bC[NT][2];          // B frags, whole tile (read at tile boundary)
    bf16x8 aP[2][2], aQ[2][2]; // A frag ping-pong (one phase ahead)

    auto stA = [&](int T, int rp) {
        const int k0   = T << 6;
        const int bufo = (T & 1) << 14;
        const int rb   = (rp ? arow1 : arow0) + srow;
        const int lb   = (rp ? ldsA1 : ldsA0) + bufo + lane * 8;
        gl2lds16(&A[(size_t)rb * K + k0 + scol],       &lds[lb]);
        gl2lds16(&A[(size_t)(rb + 8) * K + k0 + scol], &lds[lb + 512]);
    };
    auto stB = [&](int T, int pr) {   // pr0: first NT-1 loads, pr1: last 8 rows (1 load)
        const int k0   = T << 6;
        const int bufo = (T & 1) * (NT * 4096);
        if (pr == 0) {
            #pragma unroll
            for (int j = 0; j < NT - 1; ++j) {
                const int rb = brow + j * 8 + srow;
                gl2lds16(&Bw[(size_t)rb * K + k0 + scol],
                         &lds[ldsBs + j * 512 + bufo + lane * 8]);
            }
        } else {
            const int rb = brow + (NT - 1) * 8 + srow;
            gl2lds16(&Bw[(size_t)rb * K + k0 + scol],
                     &lds[ldsBs + (NT - 1) * 512 + bufo + lane * 8]);
        }
    };
    auto rdA = [&](int T, int mt, int ks) -> bf16x8 {
        int e = (mt * 16 + lm) * 64 + ks * 32 + quad * 8;
        e ^= ((e >> 6) & 7) << 3;                 // slot ^= row&7 (conflict-free)
        return *(const bf16x8*)&lds[((T & 1) << 14) + ldsAr + e];
    };
    auto rdB = [&](int T, int nt, int ks) -> bf16x8 {
        int e = (nt * 16 + lm) * 64 + ks * 32 + quad * 8;
        e ^= ((e >> 6) & 7) << 3;                 // all bases 512-elem mult: bits 6-8 clean
        return *(const bf16x8*)&lds[(T & 1) * (NT * 4096) + ldsBr + e];
    };
    auto rdBoundary = [&](int T) {
        #pragma unroll
        for (int nt = 0; nt < NT; ++nt)
            #pragma unroll
            for (int ks = 0; ks < 2; ++ks) bC[nt][ks] = rdB(T, nt, ks);
        #pragma unroll
        for (int ks = 0; ks < 2; ++ks) { aP[0][ks] = rdA(T, 0, ks); aP[1][ks] = rdA(T, 1, ks); }
    };

    // prologue: tile0 full (NT+4 loads) + tile1 first NT+2; drain tile0
    stB(0, 0); stB(0, 1); stA(0, 0); stA(0, 1);
    stB(1, 0); stB(1, 1); stA(1, 0);
    WAITVM_STEADY;
    BARRIER;
    rdBoundary(0);
    SCHED;

    #pragma unroll 1
    for (int i = 0; i < nkt; ++i) {
        // ---- P1: MFMA mt0,1 (aP); prefetch mt2,3 -> aQ ----
        if (i + 1 < nkt) stA(i + 1, 1);
        #pragma unroll
        for (int ks = 0; ks < 2; ++ks) { aQ[0][ks] = rdA(i, 2, ks); aQ[1][ks] = rdA(i, 3, ks); }
        SCHED;
        WAITLGKM(4);          // drains boundary (2NT+4); leaves aQ's 4
        MFMA_CL(0, 1, aP)
        BARRIER;
        // ---- P2: MFMA mt2,3 (aQ); prefetch mt4,5 -> aP ----  (no end barrier)
        if (i + 2 < nkt) stB(i + 2, 0);
        #pragma unroll
        for (int ks = 0; ks < 2; ++ks) { aP[0][ks] = rdA(i, 4, ks); aP[1][ks] = rdA(i, 5, ks); }
        SCHED;
        WAITLGKM(4);          // drains aQ's 4; leaves aP's 4
        MFMA_CL(2, 3, aQ)
        // ---- P3: MFMA mt4,5 (aP); prefetch mt6,7 -> aQ ----  (no end barrier)
        if (i + 2 < nkt) stB(i + 2, 1);
        #pragma unroll
        for (int ks = 0; ks < 2; ++ks) { aQ[0][ks] = rdA(i, 6, ks); aQ[1][ks] = rdA(i, 7, ks); }
        SCHED;
        WAITLGKM(4);
        MFMA_CL(4, 5, aP)
        // ---- P4: MFMA mt6,7 (aQ); boundary vmcnt; boundary reads for i+1 ----
        if (i + 2 < nkt) stA(i + 2, 0);
        SCHED;
        WAITLGKM(0);          // drains aQ's 4 (only lgkm outstanding)
        MFMA_CL(6, 7, aQ)
        SCHED;
        if (i + 2 < nkt)      { WAITVM_STEADY; }
        else if (i + 1 < nkt) { asm volatile("s_waitcnt vmcnt(0)" ::: "memory"); }
        BARRIER;
        if (i + 1 < nkt) rdBoundary(i + 1);
        SCHED;
    }

    #pragma unroll
    for (int nt = 0; nt < NT; ++nt) {
        const int col = n0 + n_ * (NT * 16) + nt * 16 + lm;
        const float bv = bias[col];
        #pragma unroll
        for (int mt = 0; mt < 8; ++mt) {
            const int rowb = m0 + m_ * 128 + mt * 16 + quad * 4;
            #pragma unroll
            for (int r = 0; r < 4; ++r) {
                const float val = acc[mt][nt][r] + bv;
                if (C_BF16)
                    ((unsigned short*)Cv)[(size_t)(rowb + r) * N + col] = f2bf(val);
                else
                    ((float*)Cv)[(size_t)(rowb + r) * N + col] = val;
            }
        }
    }
}

// ---------------- fallback GEMM (fp32 staging, round-3 proven) ----------------
template<bool A_BF16, bool C_BF16>
__global__ __launch_bounds__(256)
void gemm_bt_bias(const void* __restrict__ Av,
                  const float* __restrict__ Bw,
                  const float* __restrict__ bias,
                  void* __restrict__ Cv,
                  int M, int N, int K)
{
    __shared__ unsigned short As[128 * 40];
    __shared__ unsigned short Bs[128 * 40];

    const int tid  = threadIdx.x;
    const int m0   = blockIdx.y * 128;
    const int n0   = blockIdx.x * 128;
    const int wave = tid >> 6, lane = tid & 63;
    const int wm   = (wave >> 1) * 64;
    const int wn   = (wave & 1) * 64;
    const int lm   = lane & 15, quad = lane >> 4;

    f32x4 acc[4][4] = {};

    for (int k0 = 0; k0 < K; k0 += 32) {
        __syncthreads();
        #pragma unroll
        for (int c = 0; c < 2; ++c) {
            int chunk = tid + c * 256;
            int row   = chunk >> 2;
            int off   = (chunk & 3) * 8;
            if (A_BF16) {
                *(u16x8*)&As[row * 40 + off] =
                    *(const u16x8*)&((const unsigned short*)Av)[(size_t)(m0 + row) * K + k0 + off];
            } else {
                const float* ap = &((const float*)Av)[(size_t)(m0 + row) * K + k0 + off];
                float4 f0 = *(const float4*)ap;
                float4 f1 = *(const float4*)(ap + 4);
                u16x8 h;
                h[0]=f2bf(f0.x); h[1]=f2bf(f0.y); h[2]=f2bf(f0.z); h[3]=f2bf(f0.w);
                h[4]=f2bf(f1.x); h[5]=f2bf(f1.y); h[6]=f2bf(f1.z); h[7]=f2bf(f1.w);
                *(u16x8*)&As[row * 40 + off] = h;
            }
            {
                const float* bp = &Bw[(size_t)(n0 + row) * K + k0 + off];
                float4 f0 = *(const float4*)bp;
                float4 f1 = *(const float4*)(bp + 4);
                u16x8 h;
                h[0]=f2bf(f0.x); h[1]=f2bf(f0.y); h[2]=f2bf(f0.z); h[3]=f2bf(f0.w);
                h[4]=f2bf(f1.x); h[5]=f2bf(f1.y); h[6]=f2bf(f1.z); h[7]=f2bf(f1.w);
                *(u16x8*)&Bs[row * 40 + off] = h;
            }
        }
        __syncthreads();

        bf16x8 afr[4], bfr[4];
        #pragma unroll
        for (int i = 0; i < 4; ++i)
            afr[i] = *(const bf16x8*)&As[(wm + i * 16 + lm) * 40 + quad * 8];
        #pragma unroll
        for (int j = 0; j < 4; ++j)
            bfr[j] = *(const bf16x8*)&Bs[(wn + j * 16 + lm) * 40 + quad * 8];

        #pragma unroll
        for (int i = 0; i < 4; ++i)
            #pragma unroll
            for (int j = 0; j < 4; ++j)
                acc[i][j] = __builtin_amdgcn_mfma_f32_16x16x32_bf16(afr[i], bfr[j], acc[i][j], 0, 0, 0);
    }

    #pragma unroll
    for (int j = 0; j < 4; ++j) {
        int col = n0 + wn + j * 16 + lm;
        float bv = bias[col];
        #pragma unroll
        for (int i = 0; i < 4; ++i) {
            int rowb = m0 + wm + i * 16 + quad * 4;
            #pragma unroll
            for (int r = 0; r < 4; ++r) {
                float val = acc[i][j][r] + bv;
                if (C_BF16)
                    ((unsigned short*)Cv)[(size_t)(rowb + r) * N + col] = f2bf(val);
                else
                    ((float*)Cv)[(size_t)(rowb + r) * N + col] = val;
            }
        }
    }
}

// ---------------- Flash-style MFMA attention, GQA-grouped blocks ----------------
// r10 -> r11: one block = one KV GROUP (G=4 heads), 1024 thr = 16 waves.
// K/V staging redundancy was the structural waste: G=4 query heads share
// each KV head, but r10 gave every head its own block -> same K/V chunk
// staged 4x.  Now staging per chunk serves 4x the MFMA work (grid.y: NH->NKV,
// 1024->256 blocks).  Per-wave compute is IDENTICAL to the r10-proven code
// (16 rows x 1 head): wave w -> rowgrp w>>2, head kvh*4 + (w&3).
// K staged by threads 0-511, V-pack by 512-767 (wave-aligned ranges).
// LDS: Kl 8.7K + Vt 10.2K + Pl[16] 20.5K = 39.4 KB.  VGPR cap 128 (>84 used).
// Q-rope stays fused (once per element, r9/r10-proven numerics).
__global__ __launch_bounds__(1024)
void attn_mfma(const unsigned short* __restrict__ qkv,
               const float* __restrict__ cosb,
               const float* __restrict__ sinb,
               unsigned short* __restrict__ attn)
{
    __shared__ unsigned short Kl[CH * 136];
    __shared__ unsigned short Vt[128 * VSTR];    // [dim][row] transposed
    __shared__ unsigned short Pl[16][16 * 40];

    const int tid  = threadIdx.x;
    const int wave = tid >> 6, lane = tid & 63;
    const int lm   = lane & 15, quad = lane >> 4;
    const int kvh  = blockIdx.y;                 // 0..NKV-1
    const int b    = blockIdx.z;
    const int h    = kvh * G_ + (wave & 3);      // query head
    const int r0b  = blockIdx.x * 64;
    const int rw0  = r0b + (wave >> 2) * 16;     // wave's 16 Q-rows

    const size_t qkv_b = (size_t)b * S_ * QKV_OUT;
    const float SCL = 0.12751974f;   // (1/sqrt(128)) * log2(e)

    // Q load + in-register rope (d <-> d+64 pair is qf[kb] <-> qf[kb+2],
    // same lane: d+64 = (kb+2)*32 + quad*8 + e)
    bf16x8 qf[4];
    {
        const unsigned short* qrow = qkv + qkv_b + (size_t)(rw0 + lm) * QKV_OUT + h * D_ + quad * 8;
        u16x8 qr[4];
        #pragma unroll
        for (int kb = 0; kb < 4; ++kb)
            qr[kb] = *(const u16x8*)(qrow + kb * 32);
        const float* cb = cosb + (size_t)(rw0 + lm) * D_ + quad * 8;
        const float* sb = sinb + (size_t)(rw0 + lm) * D_ + quad * 8;
        u16x8 qo[4];
        #pragma unroll
        for (int kb = 0; kb < 2; ++kb)
            #pragma unroll
            for (int e = 0; e < 8; ++e) {
                int d = kb * 32 + e;
                float x1 = bf2f(qr[kb][e]);
                float x2 = bf2f(qr[kb + 2][e]);
                qo[kb][e]     = f2bf(x1 * cb[d]      - x2 * sb[d]);
                qo[kb + 2][e] = f2bf(x2 * cb[d + 64] + x1 * sb[d + 64]);
            }
        #pragma unroll
        for (int kb = 0; kb < 4; ++kb)
            qf[kb] = *(const bf16x8*)&qo[kb];
    }

    f32x4 O[8] = {};
    float mrow[4] = {-1e30f, -1e30f, -1e30f, -1e30f};
    float lrow[4] = {0.f, 0.f, 0.f, 0.f};

    const int c0   = max(0, r0b - (WINDOW - 1)) & ~(CH - 1);
    const int cend = r0b + 64 - CH;

    for (int c = c0; c <= cend; c += CH) {
        __syncthreads();
        // K: rows c..c+31 (already rope'd), 512 x 16B tasks by threads 0-511
        if (tid < 512) {
            int row = tid >> 4;
            int d0  = (tid & 15) * 8;
            *(u16x8*)&Kl[row * 136 + d0] =
                *(const u16x8*)(qkv + qkv_b + (size_t)(c + row) * QKV_OUT + HID + kvh * D_ + d0);
        } else if (tid < 768) {
            // V transposed: 256 tasks (2 rows x 8 dims, packed ds_write_b32)
            int t  = tid - 512;
            int r2 = (t & 15) * 2;
            int d0 = (t >> 4) * 8;
            const unsigned short* vg = qkv + qkv_b + (size_t)(c + r2) * QKV_OUT + HID + NKV * D_ + kvh * D_ + d0;
            u16x8 va = *(const u16x8*)vg;
            u16x8 vb = *(const u16x8*)(vg + QKV_OUT);
            #pragma unroll
            for (int e = 0; e < 8; ++e) {
                unsigned int pack = (unsigned int)va[e] | ((unsigned int)vb[e] << 16);
                *(unsigned int*)&Vt[(d0 + e) * VSTR + r2] = pack;
            }
        }
        __syncthreads();

        if (c + CH - 1 < rw0 - (WINDOW - 1) || c > rw0 + 15) continue;

        // QK^T: two 16-col tiles
        f32x4 s0 = {}, s1 = {};
        #pragma unroll
        for (int kb = 0; kb < 4; ++kb) {
            bf16x8 b0 = *(const bf16x8*)&Kl[lm * 136 + kb * 32 + quad * 8];
            bf16x8 b1 = *(const bf16x8*)&Kl[(16 + lm) * 136 + kb * 32 + quad * 8];
            s0 = __builtin_amdgcn_mfma_f32_16x16x32_bf16(qf[kb], b0, s0, 0, 0, 0);
            s1 = __builtin_amdgcn_mfma_f32_16x16x32_bf16(qf[kb], b1, s1, 0, 0, 0);
        }

        const int j0 = c + lm, j1 = c + 16 + lm;
        float alpha[4];
        #pragma unroll
        for (int r = 0; r < 4; ++r) {
            int row = rw0 + quad * 4 + r;
            float t0 = (j0 <= row && row - j0 < WINDOW) ? s0[r] : -3.0e38f;
            float t1 = (j1 <= row && row - j1 < WINDOW) ? s1[r] : -3.0e38f;
            float cm = fmaxf(t0, t1);
            #pragma unroll
            for (int o = 8; o >= 1; o >>= 1) cm = fmaxf(cm, __shfl_xor(cm, o, 16));
            float mnew = fmaxf(mrow[r], cm);
            float al   = exp2f((mrow[r] - mnew) * SCL);
            float p0   = exp2f((t0 - mnew) * SCL);
            float p1   = exp2f((t1 - mnew) * SCL);
            float rs   = p0 + p1;
            #pragma unroll
            for (int o = 8; o >= 1; o >>= 1) rs += __shfl_xor(rs, o, 16);
            mrow[r] = mnew;
            lrow[r] = lrow[r] * al + rs;
            alpha[r] = al;
            Pl[wave][(quad * 4 + r) * 40 + lm]      = f2bf(p0);
            Pl[wave][(quad * 4 + r) * 40 + 16 + lm] = f2bf(p1);
        }

        #pragma unroll
        for (int nt = 0; nt < 8; ++nt)
            #pragma unroll
            for (int r = 0; r < 4; ++r)
                O[nt][r] *= alpha[r];

        // PV: A = P (wave-private LDS), B = transposed V via ds_read_b128
        bf16x8 pa = *(const bf16x8*)&Pl[wave][lm * 40 + quad * 8];
        #pragma unroll
        for (int nt = 0; nt < 8; ++nt) {
            bf16x8 vbf = *(const bf16x8*)&Vt[(nt * 16 + lm) * VSTR + quad * 8];
            O[nt] = __builtin_amdgcn_mfma_f32_16x16x32_bf16(pa, vbf, O[nt], 0, 0, 0);
        }
    }

    float il[4];
    #pragma unroll
    for (int r = 0; r < 4; ++r) il[r] = 1.0f / lrow[r];
    #pragma unroll
    for (int nt = 0; nt < 8; ++nt)
        #pragma unroll
        for (int r = 0; r < 4; ++r) {
            int row = rw0 + quad * 4 + r;
            attn[(size_t)(b * S_ + row) * (NH * D_) + h * D_ + nt * 16 + lm] = f2bf(O[nt][r] * il[r]);
        }
}

extern "C" void kernel_launch(void* const* d_in, const int* in_sizes, int n_in,
                              void* d_out, int out_size, void* d_ws, size_t ws_size,
                              hipStream_t stream)
{
    const float* hidden = (const float*)d_in[0];
    const float* cosb   = (const float*)d_in[1];
    const float* sinb   = (const float*)d_in[2];
    const float* w_qkv  = (const float*)d_in[3];
    const float* b_qkv  = (const float*)d_in[4];
    const float* w_o    = (const float*)d_in[5];
    const float* b_o    = (const float*)d_in[6];
    float* out = (float*)d_out;

    unsigned char* ws = (unsigned char*)d_ws;
    const size_t QKV_B  = (size_t)M_TOT * QKV_OUT * 2;       // 25.2 MB
    const size_t ATTN_B = (size_t)M_TOT * HID * 2;           // 16.8 MB
    const size_t HB_B   = (size_t)M_TOT * HID * 2;           // 16.8 MB
    const size_t WQ_B   = (size_t)QKV_OUT * HID * 2;         // 50.3 MB
    const size_t WO_B   = (size_t)HID * HID * 2;             // 33.6 MB
    const size_t NEED   = QKV_B + ATTN_B + HB_B + WQ_B;      // aliased-wo layout
    const size_t NEED2  = NEED + WO_B;                        // separate-wo layout

    unsigned short* qkv_ws  = (unsigned short*)(ws);
    unsigned short* attn_ws = (unsigned short*)(ws + QKV_B);

    dim3 blk(256);
    int n8h = M_TOT * HID / 8;
    int n8q = QKV_OUT * HID / 8;
    int n8o = HID * HID / 8;
    const int ropek_blocks = (M_TOT * NKV * 64) / 256;

    if (ws_size >= NEED2) {
        // fused path: 5 launches total
        unsigned short* hb = (unsigned short*)(ws + QKV_B + ATTN_B);
        unsigned short* wq = (unsigned short*)(ws + QKV_B + ATTN_B + HB_B);
        unsigned short* wo = (unsigned short*)(ws + QKV_B + ATTN_B + HB_B + WQ_B);

        conv3_f32_bf16<<<dim3((n8h + n8q + n8o) / 256), blk, 0, stream>>>(
            hidden, hb, n8h, w_qkv, wq, n8q, w_o, wo, n8o);
        gemm256_8ph<3, true><<<dim3(QKV_OUT / 192, M_TOT / 256), dim3(512), 0, stream>>>(
            hb, wq, b_qkv, qkv_ws, M_TOT, QKV_OUT, HID);
        rope_k_kernel<<<dim3(ropek_blocks), blk, 0, stream>>>(qkv_ws, cosb, sinb);
        attn_mfma<<<dim3(S_ / 64, NKV, B_), dim3(1024), 0, stream>>>(qkv_ws, cosb, sinb, attn_ws);
        gemm256_8ph<2, false><<<dim3(HID / 128, M_TOT / 256), dim3(512), 0, stream>>>(
            attn_ws, wo, b_o, out, M_TOT, HID, NH * D_);
    } else if (ws_size >= NEED && WO_B <= HB_B + WQ_B) {
        // r8 layout: wo aliases hb+wq region after gemm1
        unsigned short* hb = (unsigned short*)(ws + QKV_B + ATTN_B);
        unsigned short* wq = (unsigned short*)(ws + QKV_B + ATTN_B + HB_B);
        unsigned short* wo = (unsigned short*)(ws + QKV_B + ATTN_B);

        conv_f32_bf16<<<dim3((n8h + 255) / 256), blk, 0, stream>>>(hidden, hb, n8h);
        conv_f32_bf16<<<dim3((n8q + 255) / 256), blk, 0, stream>>>(w_qkv, wq, n8q);
        gemm256_8ph<3, true><<<dim3(QKV_OUT / 192, M_TOT / 256), dim3(512), 0, stream>>>(
            hb, wq, b_qkv, qkv_ws, M_TOT, QKV_OUT, HID);
        conv_f32_bf16<<<dim3((n8o + 255) / 256), blk, 0, stream>>>(w_o, wo, n8o);
        rope_k_kernel<<<dim3(ropek_blocks), blk, 0, stream>>>(qkv_ws, cosb, sinb);
        attn_mfma<<<dim3(S_ / 64, NKV, B_), dim3(1024), 0, stream>>>(qkv_ws, cosb, sinb, attn_ws);
        gemm256_8ph<2, false><<<dim3(HID / 128, M_TOT / 256), dim3(512), 0, stream>>>(
            attn_ws, wo, b_o, out, M_TOT, HID, NH * D_);
    } else {
        gemm_bt_bias<false, true><<<dim3(QKV_OUT / 128, M_TOT / 128), blk, 0, stream>>>(
            hidden, w_qkv, b_qkv, qkv_ws, M_TOT, QKV_OUT, HID);
        rope_k_kernel<<<dim3(ropek_blocks), blk, 0, stream>>>(qkv_ws, cosb, sinb);
        attn_mfma<<<dim3(S_ / 64, NKV, B_), dim3(1024), 0, stream>>>(qkv_ws, cosb, sinb, attn_ws);
        gemm_bt_bias<true, false><<<dim3(HID / 128, M_TOT / 128), blk, 0, stream>>>(
            attn_ws, w_o, b_o, out, M_TOT, HID, NH * D_);
    }
}